// Round 16
// baseline (77.000 us; speedup 1.0000x reference)
//
#include <hip/hip_runtime.h>

// ---------------------------------------------------------------------------
// Chamfer_Loss: chamfer(pred,tgt) + W_EDGE*edge + W_LAP*cotLap + W_NORMAL*nc
//               + W_VEL*chamfer(diff(pred), diff(tgt))
// B=2, N=8281 (g=91), fp32 in/out. Output: 1 scalar.
// R16: R10 structure (best: 50.5us chamfer, 71.5 total) with the MFMAs moved
//     to inline asm with VGPR DESTINATIONS. R10's VALUBusy=52% = ~119cyc/tile
//     vs ~22cyc of source-level work: compiler kept accumulators in AGPRs
//     (VGPR_Count 44) and burned issue slots on v_accvgpr_read per tile.
//     gfx950 unified file allows v-dst MFMA; asm forces it. Hazard nops
//     (s_nop 7/7/2) included inside the asm (compiler can't see through it).
//     mesh/finalize/bprep unchanged from the R10/R12 layout (unfused).
// ---------------------------------------------------------------------------

typedef unsigned int uint32;
typedef __attribute__((ext_vector_type(8)))  short bf16x8;
typedef __attribute__((ext_vector_type(16))) float f32x16;

#define W_EDGE   0.5f
#define W_LAP    0.05f
#define W_NORMAL 0.01f
#define W_VEL    10.0f
#define BIGF     3.0e38f
#define RSTRIDE  8320      // padded row stride (>= 8281, 8320 = 65*128)

__device__ __forceinline__ unsigned short f2bf(float f){
    uint32 b = __float_as_uint(f);
    b += 0x7FFFu + ((b >> 16) & 1u);          // RNE
    return (unsigned short)(b >> 16);
}
__device__ __forceinline__ float bf2f(unsigned short h){
    return __uint_as_float(((uint32)h) << 16);
}

__device__ __forceinline__ float wave_sum(float v) {
#pragma unroll
    for (int o = 32; o > 0; o >>= 1) v += __shfl_down(v, o, 64);
    return v;
}

// ---------------------------------------------------------------------------
// B-fragment prep + workspace zeroing (fused; disjoint memory, same dispatch).
// combo c = dir*4 + ds*2 + b; dir 0: y-side = tgt, dir 1: y-side = pred.
// K-slot map (A-side in chamfer kernel):
//  k0-2: A=-2xh B=yh | k3-5: A=-2xl B=yh | k6-8: A=-2xh B=yl
//  k9:   A=xxh  B=1  | k10:  A=xxl B=1  | k11: A=1 B=yyh | k12: A=1 B=yyl
//  k13-15: 0.   acc = xx + yy - 2 x.y = d  (pad col: yy=BIG => never min)
// Lane l: col = l&31, holds k = (l>>5)*8 + i.
// ---------------------------------------------------------------------------
__global__ void bprep_k(const float* __restrict__ pred, const float* __restrict__ tgt,
                        int N, uint4* __restrict__ bfrag,
                        float* __restrict__ ws, int nzero)
{
    // grid-stride zero of [accum+counter | Lx | rowsum]
    {
        uint32* w = (uint32*)ws;
        for (int i = blockIdx.x * blockDim.x + threadIdx.x; i < nzero;
             i += gridDim.x * blockDim.x)
            w[i] = 0u;
    }

    const int NT = (N + 31) >> 5;
    const int gt = blockIdx.x * 4 + (threadIdx.x >> 6);
    if (gt >= 8 * NT) return;
    const int c = gt / NT, t = gt - c * NT;
    const int dir = c >> 2, ds = (c >> 1) & 1, b = c & 1;
    const int Np = N - ds;
    const int l = threadIdx.x & 63;
    const int col = t * 32 + (l & 31);
    const float* __restrict__ yb = (dir ? pred : tgt) + (size_t)b * N * 3;
    float y0 = 0.f, y1 = 0.f, y2 = 0.f;
    const bool valid = col < Np;
    if (valid){
        if (ds){
            y0 = yb[(col+1)*3+0] - yb[col*3+0];
            y1 = yb[(col+1)*3+1] - yb[col*3+1];
            y2 = yb[(col+1)*3+2] - yb[col*3+2];
        } else {
            y0 = yb[col*3+0]; y1 = yb[col*3+1]; y2 = yb[col*3+2];
        }
    }
    const float yy = fmaf(y0,y0, fmaf(y1,y1, y2*y2));
    unsigned short yh0=f2bf(y0), yh1=f2bf(y1), yh2=f2bf(y2);
    unsigned short yl0=f2bf(y0-bf2f(yh0)), yl1=f2bf(y1-bf2f(yh1)), yl2=f2bf(y2-bf2f(yh2));
    unsigned short yyh, yyl;
    if (valid){ yyh = f2bf(yy); yyl = f2bf(yy - bf2f(yyh)); }
    else      { yyh = f2bf(BIGF); yyl = 0; }
    const short ONE = (short)0x3F80;
    bf16x8 Bu;
    if (l < 32){        // k0-7
        Bu[0]=(short)yh0; Bu[1]=(short)yh1; Bu[2]=(short)yh2;
        Bu[3]=(short)yh0; Bu[4]=(short)yh1; Bu[5]=(short)yh2;
        Bu[6]=(short)yl0; Bu[7]=(short)yl1;
    } else {            // k8-15
        Bu[0]=(short)yl2; Bu[1]=ONE; Bu[2]=ONE; Bu[3]=(short)yyh; Bu[4]=(short)yyl;
        Bu[5]=0; Bu[6]=0; Bu[7]=0;
    }
    bfrag[(size_t)(c * NT + t) * 64 + l] = __builtin_bit_cast(uint4, Bu);
}

// ---------------------------------------------------------------------------
// MFMA chamfer, row-min only. grid (65, 4, 8), 256 thr = 4 waves.
// R10 structure: 8-load batches, MFMA pairs + sched_barrier(0). MFMAs are
// inline asm with VGPR destinations (no AGPRs -> no v_accvgpr_read storm).
// Hazard nops for VALU-read-after-MFMA-write included in the asm.
// rowpart[c][chunk][row] = min_{cols in chunk} d(row, col)
// ---------------------------------------------------------------------------
__global__ __launch_bounds__(256)
void chamfer_mfma_k(const float* __restrict__ pred, const float* __restrict__ tgt,
                    int N, const uint4* __restrict__ bfrag,
                    float* __restrict__ rowpart)
{
    const int c = blockIdx.z;
    const int dir = c >> 2, ds = (c >> 1) & 1, b = c & 1;
    const int Np = N - ds;
    const int NT = (N + 31) >> 5;            // 259
    const int TC = (NT + 3) >> 2;            // 65
    const int t0 = blockIdx.y * TC;
    const int t1 = min(NT, t0 + TC);
    const int w = threadIdx.x >> 6, l = threadIdx.x & 63;
    const int h = l >> 5;
    const int grow = blockIdx.x * 128 + w * 32 + (l & 31);

    const float* __restrict__ xb = (dir ? tgt : pred) + (size_t)b * N * 3;
    float a0 = 0.f, a1 = 0.f, a2 = 0.f;
    const bool xvalid = grow < Np;
    if (xvalid){
        if (ds){
            a0 = xb[(grow+1)*3+0] - xb[grow*3+0];
            a1 = xb[(grow+1)*3+1] - xb[grow*3+1];
            a2 = xb[(grow+1)*3+2] - xb[grow*3+2];
        } else {
            a0 = xb[grow*3+0]; a1 = xb[grow*3+1]; a2 = xb[grow*3+2];
        }
    }
    const float xx = fmaf(a0,a0, fmaf(a1,a1, a2*a2));
    unsigned short xh0=f2bf(a0), xh1=f2bf(a1), xh2=f2bf(a2);
    unsigned short nxh0=f2bf(-2.f*bf2f(xh0)), nxh1=f2bf(-2.f*bf2f(xh1)), nxh2=f2bf(-2.f*bf2f(xh2));
    unsigned short nxl0=f2bf(-2.f*(a0-bf2f(xh0))), nxl1=f2bf(-2.f*(a1-bf2f(xh1))),
                   nxl2=f2bf(-2.f*(a2-bf2f(xh2)));
    unsigned short xxh=f2bf(xx), xxl=f2bf(xx-bf2f(xxh));
    const short ONE = (short)0x3F80;
    bf16x8 A;
    if (h == 0){   // k0-7
        A[0]=(short)nxh0; A[1]=(short)nxh1; A[2]=(short)nxh2;
        A[3]=(short)nxl0; A[4]=(short)nxl1; A[5]=(short)nxl2;
        A[6]=(short)nxh0; A[7]=(short)nxh1;
    } else {       // k8-15
        A[0]=(short)nxh2; A[1]=(short)xxh; A[2]=(short)xxl;
        A[3]=ONE; A[4]=ONE; A[5]=0; A[6]=0; A[7]=0;
    }

    f32x16 zacc;
#pragma unroll
    for (int r = 0; r < 16; ++r) zacc[r] = 0.f;
    float rm[16];
#pragma unroll
    for (int r = 0; r < 16; ++r) rm[r] = BIGF;

    const uint4* __restrict__ bfp = bfrag + (size_t)c * NT * 64 + l;

    const int ntile = t1 - t0;
    const int nb = ntile >> 3;               // full 8-tile batches

    // Two v-dst MFMAs per asm block; s_nop 7/7/2 (19cyc) covers the
    // VALU-read-after-MFMA-write hazard (compiler can't see into asm).
#define PAIR_ASM(Ta, Tb)                                                    \
    {                                                                       \
        f32x16 u0, u1;                                                      \
        asm("v_mfma_f32_32x32x16_bf16 %0, %2, %3, %5\n\t"                   \
            "v_mfma_f32_32x32x16_bf16 %1, %2, %4, %5\n\t"                   \
            "s_nop 7\n\t"                                                   \
            "s_nop 7\n\t"                                                   \
            "s_nop 2"                                                       \
            : "=&v"(u0), "=&v"(u1)                                          \
            : "v"(A), "v"(__builtin_bit_cast(bf16x8, Ta)),                  \
              "v"(__builtin_bit_cast(bf16x8, Tb)), "v"(zacc));              \
        _Pragma("unroll")                                                   \
        for (int r = 0; r < 16; ++r)                                        \
            rm[r] = fminf(fminf(rm[r], u0[r]), u1[r]);                      \
    }                                                                       \
    __builtin_amdgcn_sched_barrier(0);

    int t = t0;
    for (int bt = 0; bt < nb; ++bt, t += 8){
        // issue all 8 tile loads up-front (independent, stay in flight)
        const uint4 T0 = bfp[(size_t)(t+0)*64];
        const uint4 T1 = bfp[(size_t)(t+1)*64];
        const uint4 T2 = bfp[(size_t)(t+2)*64];
        const uint4 T3 = bfp[(size_t)(t+3)*64];
        const uint4 T4 = bfp[(size_t)(t+4)*64];
        const uint4 T5 = bfp[(size_t)(t+5)*64];
        const uint4 T6 = bfp[(size_t)(t+6)*64];
        const uint4 T7 = bfp[(size_t)(t+7)*64];
        PAIR_ASM(T0, T1)
        PAIR_ASM(T2, T3)
        PAIR_ASM(T4, T5)
        PAIR_ASM(T6, T7)
    }
#undef PAIR_ASM

    // leftover tiles (<8)
    for (; t < t1; ++t){
        const uint4 Tb = bfp[(size_t)t * 64];
        f32x16 u0;
        asm("v_mfma_f32_32x32x16_bf16 %0, %1, %2, %3\n\t"
            "s_nop 7\n\t"
            "s_nop 7\n\t"
            "s_nop 2"
            : "=&v"(u0)
            : "v"(A), "v"(__builtin_bit_cast(bf16x8, Tb)), "v"(zacc));
#pragma unroll
        for (int r = 0; r < 16; ++r) rm[r] = fminf(rm[r], u0[r]);
    }

    // row-min butterfly within each 32-lane half (cols live across lanes)
#pragma unroll
    for (int r = 0; r < 16; ++r){
        float v = rm[r];
        v = fminf(v, __shfl_xor(v, 1, 64));
        v = fminf(v, __shfl_xor(v, 2, 64));
        v = fminf(v, __shfl_xor(v, 4, 64));
        v = fminf(v, __shfl_xor(v, 8, 64));
        v = fminf(v, __shfl_xor(v, 16, 64));
        rm[r] = v;
    }
    float* __restrict__ rp = rowpart + (size_t)(c * 4 + blockIdx.y) * RSTRIDE;
#pragma unroll
    for (int r = 0; r < 16; ++r){             // static index only (no scratch)
        if ((l & 31) == r){
            const int rowl = (r & 3) + 8 * (r >> 2) + 4 * h;
            const int gr = blockIdx.x * 128 + w * 32 + rowl;
            if (gr < Np) rp[gr] = rm[r];
        }
    }
}

// edge loss + normal consistency + laplacian cot scatter, one dispatch.
__global__ void mesh_k(const float* __restrict__ pred,
                       const int* __restrict__ edges, int E,
                       const int* __restrict__ pairs, int P,
                       const int* __restrict__ faces, int F,
                       int N, int B, float scaleE, float scaleP,
                       float* __restrict__ Lx, float* __restrict__ rowsum,
                       float* __restrict__ accum)
{
    const int tE = B * E, tP = B * P, tF = B * F;
    const int total = tE + tP + tF;
    float se = 0.f, sp = 0.f;
    for (int idx = blockIdx.x * blockDim.x + threadIdx.x; idx < total;
         idx += gridDim.x * blockDim.x) {
        if (idx < tE) {
            const int b = idx / E;
            const int e = idx - b * E;
            const float* __restrict__ vb = pred + (size_t)b * N * 3;
            const int i0 = edges[e * 2 + 0], i1 = edges[e * 2 + 1];
            float dx = vb[i0 * 3 + 0] - vb[i1 * 3 + 0];
            float dy = vb[i0 * 3 + 1] - vb[i1 * 3 + 1];
            float dz = vb[i0 * 3 + 2] - vb[i1 * 3 + 2];
            se += fmaf(dx, dx, fmaf(dy, dy, dz * dz));
        } else if (idx < tE + tP) {
            const int q = idx - tE;
            const int b = q / P;
            const int p = q - b * P;
            const float* __restrict__ vb = pred + (size_t)b * N * 3;
            const int a0 = pairs[p * 4 + 0], a1 = pairs[p * 4 + 1];
            const int a2 = pairs[p * 4 + 2], a3 = pairs[p * 4 + 3];
            float p0x = vb[a0 * 3], p0y = vb[a0 * 3 + 1], p0z = vb[a0 * 3 + 2];
            float ex = vb[a1 * 3] - p0x, ey = vb[a1 * 3 + 1] - p0y, ez = vb[a1 * 3 + 2] - p0z;
            float ux = vb[a2 * 3] - p0x, uy = vb[a2 * 3 + 1] - p0y, uz = vb[a2 * 3 + 2] - p0z;
            float wx = vb[a3 * 3] - p0x, wy = vb[a3 * 3 + 1] - p0y, wz = vb[a3 * 3 + 2] - p0z;
            float n0x = ey * uz - ez * uy;
            float n0y = ez * ux - ex * uz;
            float n0z = ex * uy - ey * ux;
            float n1x = -(ey * wz - ez * wy);
            float n1y = -(ez * wx - ex * wz);
            float n1z = -(ex * wy - ey * wx);
            float dt = n0x * n1x + n0y * n1y + n0z * n1z;
            float l0 = sqrtf(n0x * n0x + n0y * n0y + n0z * n0z);
            float l1 = sqrtf(n1x * n1x + n1y * n1y + n1z * n1z);
            sp += 1.0f - dt / (fmaxf(l0, 1e-8f) * fmaxf(l1, 1e-8f));
        } else {
            const int q = idx - tE - tP;
            const int b = q / F;
            const int f = q - b * F;
            const float* __restrict__ vb = pred + (size_t)b * N * 3;
            const int i0 = faces[f * 3 + 0], i1 = faces[f * 3 + 1], i2 = faces[f * 3 + 2];
            float v0x = vb[i0 * 3], v0y = vb[i0 * 3 + 1], v0z = vb[i0 * 3 + 2];
            float v1x = vb[i1 * 3], v1y = vb[i1 * 3 + 1], v1z = vb[i1 * 3 + 2];
            float v2x = vb[i2 * 3], v2y = vb[i2 * 3 + 1], v2z = vb[i2 * 3 + 2];
            float ax = v1x - v2x, ay = v1y - v2y, az = v1z - v2z;
            float bx = v0x - v2x, by = v0y - v2y, bz = v0z - v2z;
            float cx = v0x - v1x, cy = v0y - v1y, cz = v0z - v1z;
            float A  = sqrtf(ax * ax + ay * ay + az * az);
            float Bl = sqrtf(bx * bx + by * by + bz * bz);
            float C  = sqrtf(cx * cx + cy * cy + cz * cz);
            float s2 = 0.5f * (A + Bl + C);
            float area = sqrtf(fmaxf(s2 * (s2 - A) * (s2 - Bl) * (s2 - C), 1e-12f));
            float A2 = A * A, B2 = Bl * Bl, C2 = C * C;
            float inv4a = 1.0f / (4.0f * area);
            float cota = (B2 + C2 - A2) * inv4a;
            float cotb = (A2 + C2 - B2) * inv4a;
            float cotc = (A2 + B2 - C2) * inv4a;

            float* __restrict__ Lb = Lx + (size_t)b * N * 3;
            float* __restrict__ rb = rowsum + (size_t)b * N;
            #define SCAT(i, j, wv)                                            \
                atomicAdd(&Lb[(i) * 3 + 0], (wv) * vb[(j) * 3 + 0]);          \
                atomicAdd(&Lb[(i) * 3 + 1], (wv) * vb[(j) * 3 + 1]);          \
                atomicAdd(&Lb[(i) * 3 + 2], (wv) * vb[(j) * 3 + 2]);          \
                atomicAdd(&rb[(i)], (wv));
            SCAT(i1, i2, cota) SCAT(i2, i1, cota)
            SCAT(i2, i0, cotb) SCAT(i0, i2, cotb)
            SCAT(i0, i1, cotc) SCAT(i1, i0, cotc)
            #undef SCAT
        }
    }
    se = wave_sum(se);
    sp = wave_sum(sp);
    if ((threadIdx.x & 63) == 0) atomicAdd(accum, fmaf(se, scaleE, sp * scaleP));
}

// rowpart 4-chunk min + clamp + lap residual; last block writes d_out.
__global__ void finalize_k(const float* __restrict__ rowpart,
                           const float* __restrict__ pred, const float* __restrict__ Lx,
                           const float* __restrict__ rowsum,
                           int N, float sMain, float sVel, float scaleL,
                           float* __restrict__ accum, float* __restrict__ out)
{
    const int total = 8 * N + 2 * N;
    float sm = 0.f, sv = 0.f, sl = 0.f;
    for (int idx = blockIdx.x * blockDim.x + threadIdx.x; idx < total;
         idx += gridDim.x * blockDim.x) {
        if (idx < 8 * N) {
            const int c = idx / N, i = idx - c * N;
            const int ds = (c >> 1) & 1;
            if (i < N - ds) {
                const float* rp = rowpart + (size_t)c * 4 * RSTRIDE;
                float v = fminf(fminf(rp[i], rp[RSTRIDE + i]),
                                fminf(rp[2*RSTRIDE + i], rp[3*RSTRIDE + i]));
                float d = fmaxf(v, 0.f);
                if (ds) sv += d; else sm += d;
            }
        } else {
            const int q = idx - 8 * N;       // B*N lap entries
            float rs = rowsum[q];
            float nw = rs > 0.f ? 1.0f / rs : 0.f;
            float rx = Lx[q*3+0]*nw - pred[q*3+0];
            float ry = Lx[q*3+1]*nw - pred[q*3+1];
            float rz = Lx[q*3+2]*nw - pred[q*3+2];
            sl += sqrtf(rx*rx + ry*ry + rz*rz);
        }
    }
    sm = wave_sum(sm); sv = wave_sum(sv); sl = wave_sum(sl);
    if ((threadIdx.x & 63) == 0)
        atomicAdd(accum, fmaf(sm, sMain, fmaf(sv, sVel, sl * scaleL)));

    // last block writes the output (accum[4] is the completion counter,
    // zeroed by bprep_k's ws-zero each launch)
    __syncthreads();
    if (threadIdx.x == 0){
        __threadfence();
        const uint32 prev = atomicAdd((uint32*)(accum + 4), 1u);
        if (prev == gridDim.x - 1)
            out[0] = atomicAdd(accum, 0.0f);   // coherent read of final sum
    }
}

extern "C" void kernel_launch(void* const* d_in, const int* in_sizes, int n_in,
                              void* d_out, int out_size, void* d_ws, size_t ws_size,
                              hipStream_t stream)
{
    const float* pred = (const float*)d_in[0];
    const float* tgt  = (const float*)d_in[1];
    const int* faces  = (const int*)d_in[2];
    const int* edges  = (const int*)d_in[3];
    const int* pairs  = (const int*)d_in[4];

    const int B = 2;
    const int N = in_sizes[0] / (3 * B);   // 8281
    const int F = in_sizes[2] / 3;
    const int E = in_sizes[3] / 2;
    const int P = in_sizes[4] / 4;
    const int NT = (N + 31) >> 5;          // 259

    // workspace layout (4B units):
    // [accum 8 (incl counter at +4)][Lx B*N*3][rowsum B*N][rowpart 32*RSTRIDE][bfrag]
    float* ws      = (float*)d_ws;
    float* accum   = ws;
    float* Lx      = ws + 8;
    float* rowsum  = Lx + (size_t)B * N * 3;
    float* rowpart = rowsum + (size_t)B * N;
    size_t off     = 8 + (size_t)B*N*3 + (size_t)B*N + (size_t)32*RSTRIDE;
    uint4* bfrag   = (uint4*)(ws + off);   // off*4 16B-aligned (off div by 4)

    const int nzero = 8 + B * N * 3 + B * N;

    bprep_k<<<dim3((8 * NT + 3) / 4), dim3(256), 0, stream>>>(pred, tgt, N, bfrag,
                                                              ws, nzero);

    chamfer_mfma_k<<<dim3((N + 127) / 128, 4, 8), dim3(256), 0, stream>>>(
        pred, tgt, N, bfrag, rowpart);

    mesh_k<<<128, dim3(256), 0, stream>>>(pred, edges, E, pairs, P, faces, F, N, B,
                                          W_EDGE / ((float)B * (float)E),
                                          W_NORMAL / ((float)B * (float)P),
                                          Lx, rowsum, accum);

    finalize_k<<<96, dim3(256), 0, stream>>>(rowpart, pred, Lx, rowsum, N,
                                             1.0f / ((float)B * (float)N),
                                             W_VEL / ((float)B * (float)(N - 1)),
                                             W_LAP / ((float)B * (float)N),
                                             accum, (float*)d_out);
}

// Round 17
// 74.119 us; speedup vs baseline: 1.0389x; 1.0389x over previous
//
#include <hip/hip_runtime.h>

// ---------------------------------------------------------------------------
// Chamfer_Loss: chamfer(pred,tgt) + W_EDGE*edge + W_LAP*cotLap + W_NORMAL*nc
//               + W_VEL*chamfer(diff(pred), diff(tgt))
// B=2, N=8281 (g=91), fp32 in/out. Output: 1 scalar.
// R17: LDS staging via global_load_lds (async, no VGPR round-trip), double
//     buffered. R16 proved the chamfer is pure L2-latency bound (VALUBusy
//     halved -> duration unchanged). bfrag layout matches global_load_lds
//     exactly (per-lane gaddr = base + l*16, LDS dst = uniform + lane*16).
//     Each block stages each tile ONCE (4x less L2 traffic); compute reads
//     ds_read_b128 (~12cyc) instead of L2 (~200cyc). T3 2-phase recipe:
//     {stage next | compute cur | barrier | swap}. R11's failure was
//     reg-staging+launch_bounds spill, NOT LDS. MFMA back to intrinsics.
// ---------------------------------------------------------------------------

typedef unsigned int uint32;
typedef __attribute__((ext_vector_type(8)))  short bf16x8;
typedef __attribute__((ext_vector_type(16))) float f32x16;

#define W_EDGE   0.5f
#define W_LAP    0.05f
#define W_NORMAL 0.01f
#define W_VEL    10.0f
#define BIGF     3.0e38f
#define RSTRIDE  8320      // padded row stride (>= 8281, 8320 = 65*128)

__device__ __forceinline__ unsigned short f2bf(float f){
    uint32 b = __float_as_uint(f);
    b += 0x7FFFu + ((b >> 16) & 1u);          // RNE
    return (unsigned short)(b >> 16);
}
__device__ __forceinline__ float bf2f(unsigned short h){
    return __uint_as_float(((uint32)h) << 16);
}

__device__ __forceinline__ float wave_sum(float v) {
#pragma unroll
    for (int o = 32; o > 0; o >>= 1) v += __shfl_down(v, o, 64);
    return v;
}

// async global->LDS, 16B per lane: lane l reads g[l] (16B) -> lds_base + l*16
__device__ __forceinline__ void gload_lds16(const uint4* __restrict__ g, uint4* l){
    __builtin_amdgcn_global_load_lds(
        (const __attribute__((address_space(1))) void*)g,
        (__attribute__((address_space(3))) void*)l, 16, 0, 0);
}

// ---------------------------------------------------------------------------
// B-fragment prep + workspace zeroing (fused; disjoint memory, same dispatch).
// combo c = dir*4 + ds*2 + b; dir 0: y-side = tgt, dir 1: y-side = pred.
// K-slot map (A-side in chamfer kernel):
//  k0-2: A=-2xh B=yh | k3-5: A=-2xl B=yh | k6-8: A=-2xh B=yl
//  k9:   A=xxh  B=1  | k10:  A=xxl B=1  | k11: A=1 B=yyh | k12: A=1 B=yyl
//  k13-15: 0.   acc = xx + yy - 2 x.y = d  (pad col: yy=BIG => never min)
// Lane l: col = l&31, holds k = (l>>5)*8 + i.
// ---------------------------------------------------------------------------
__global__ void bprep_k(const float* __restrict__ pred, const float* __restrict__ tgt,
                        int N, uint4* __restrict__ bfrag,
                        float* __restrict__ ws, int nzero)
{
    // grid-stride zero of [accum+counter | Lx | rowsum]
    {
        uint32* w = (uint32*)ws;
        for (int i = blockIdx.x * blockDim.x + threadIdx.x; i < nzero;
             i += gridDim.x * blockDim.x)
            w[i] = 0u;
    }

    const int NT = (N + 31) >> 5;
    const int gt = blockIdx.x * 4 + (threadIdx.x >> 6);
    if (gt >= 8 * NT) return;
    const int c = gt / NT, t = gt - c * NT;
    const int dir = c >> 2, ds = (c >> 1) & 1, b = c & 1;
    const int Np = N - ds;
    const int l = threadIdx.x & 63;
    const int col = t * 32 + (l & 31);
    const float* __restrict__ yb = (dir ? pred : tgt) + (size_t)b * N * 3;
    float y0 = 0.f, y1 = 0.f, y2 = 0.f;
    const bool valid = col < Np;
    if (valid){
        if (ds){
            y0 = yb[(col+1)*3+0] - yb[col*3+0];
            y1 = yb[(col+1)*3+1] - yb[col*3+1];
            y2 = yb[(col+1)*3+2] - yb[col*3+2];
        } else {
            y0 = yb[col*3+0]; y1 = yb[col*3+1]; y2 = yb[col*3+2];
        }
    }
    const float yy = fmaf(y0,y0, fmaf(y1,y1, y2*y2));
    unsigned short yh0=f2bf(y0), yh1=f2bf(y1), yh2=f2bf(y2);
    unsigned short yl0=f2bf(y0-bf2f(yh0)), yl1=f2bf(y1-bf2f(yh1)), yl2=f2bf(y2-bf2f(yh2));
    unsigned short yyh, yyl;
    if (valid){ yyh = f2bf(yy); yyl = f2bf(yy - bf2f(yyh)); }
    else      { yyh = f2bf(BIGF); yyl = 0; }
    const short ONE = (short)0x3F80;
    bf16x8 Bu;
    if (l < 32){        // k0-7
        Bu[0]=(short)yh0; Bu[1]=(short)yh1; Bu[2]=(short)yh2;
        Bu[3]=(short)yh0; Bu[4]=(short)yh1; Bu[5]=(short)yh2;
        Bu[6]=(short)yl0; Bu[7]=(short)yl1;
    } else {            // k8-15
        Bu[0]=(short)yl2; Bu[1]=ONE; Bu[2]=ONE; Bu[3]=(short)yyh; Bu[4]=(short)yyl;
        Bu[5]=0; Bu[6]=0; Bu[7]=0;
    }
    bfrag[(size_t)(c * NT + t) * 64 + l] = __builtin_bit_cast(uint4, Bu);
}

// ---------------------------------------------------------------------------
// MFMA chamfer, row-min only. grid (65, 4, 8), 256 thr = 4 waves.
// Double-buffered LDS staging via global_load_lds: per batch of 8 tiles,
// wave w stages tiles {2w, 2w+1} (2 async instrs, no VGPRs); compute reads
// ds_read_b128 from LDS; one __syncthreads per batch (implicit vmcnt drain
// waits the NEXT batch's loads, which had the whole compute phase in flight).
// rowpart[c][chunk][row] = min_{cols in chunk} d(row, col)
// ---------------------------------------------------------------------------
__global__ __launch_bounds__(256)
void chamfer_mfma_k(const float* __restrict__ pred, const float* __restrict__ tgt,
                    int N, const uint4* __restrict__ bfrag,
                    float* __restrict__ rowpart)
{
    const int c = blockIdx.z;
    const int dir = c >> 2, ds = (c >> 1) & 1, b = c & 1;
    const int Np = N - ds;
    const int NT = (N + 31) >> 5;            // 259
    const int TC = (NT + 3) >> 2;            // 65
    const int t0 = blockIdx.y * TC;
    const int t1 = min(NT, t0 + TC);
    const int w = threadIdx.x >> 6, l = threadIdx.x & 63;
    const int h = l >> 5;
    const int grow = blockIdx.x * 128 + w * 32 + (l & 31);

    const float* __restrict__ xb = (dir ? tgt : pred) + (size_t)b * N * 3;
    float a0 = 0.f, a1 = 0.f, a2 = 0.f;
    const bool xvalid = grow < Np;
    if (xvalid){
        if (ds){
            a0 = xb[(grow+1)*3+0] - xb[grow*3+0];
            a1 = xb[(grow+1)*3+1] - xb[grow*3+1];
            a2 = xb[(grow+1)*3+2] - xb[grow*3+2];
        } else {
            a0 = xb[grow*3+0]; a1 = xb[grow*3+1]; a2 = xb[grow*3+2];
        }
    }
    const float xx = fmaf(a0,a0, fmaf(a1,a1, a2*a2));
    unsigned short xh0=f2bf(a0), xh1=f2bf(a1), xh2=f2bf(a2);
    unsigned short nxh0=f2bf(-2.f*bf2f(xh0)), nxh1=f2bf(-2.f*bf2f(xh1)), nxh2=f2bf(-2.f*bf2f(xh2));
    unsigned short nxl0=f2bf(-2.f*(a0-bf2f(xh0))), nxl1=f2bf(-2.f*(a1-bf2f(xh1))),
                   nxl2=f2bf(-2.f*(a2-bf2f(xh2)));
    unsigned short xxh=f2bf(xx), xxl=f2bf(xx-bf2f(xxh));
    const short ONE = (short)0x3F80;
    bf16x8 A;
    if (h == 0){   // k0-7
        A[0]=(short)nxh0; A[1]=(short)nxh1; A[2]=(short)nxh2;
        A[3]=(short)nxl0; A[4]=(short)nxl1; A[5]=(short)nxl2;
        A[6]=(short)nxh0; A[7]=(short)nxh1;
    } else {       // k8-15
        A[0]=(short)nxh2; A[1]=(short)xxh; A[2]=(short)xxl;
        A[3]=ONE; A[4]=ONE; A[5]=0; A[6]=0; A[7]=0;
    }

    f32x16 zacc;
#pragma unroll
    for (int r = 0; r < 16; ++r) zacc[r] = 0.f;
    float rm[16];
#pragma unroll
    for (int r = 0; r < 16; ++r) rm[r] = BIGF;

    const uint4* __restrict__ bfp = bfrag + (size_t)c * NT * 64 + l;

    __shared__ uint4 sbuf[2][512];           // 2 buffers x 8 tiles x 64 lanes
    const int ntile = t1 - t0;
    const int nb = ntile >> 3;               // full 8-tile batches

    // wave w stages tiles {2w, 2w+1} of a batch into sbuf[bi]
#define STAGE(bi, tbase)                                                    \
    gload_lds16(bfp + (size_t)((tbase) + 2*w    ) * 64, &sbuf[bi][(2*w    )*64]); \
    gload_lds16(bfp + (size_t)((tbase) + 2*w + 1) * 64, &sbuf[bi][(2*w + 1)*64]);

#define PAIRC(bi, i0_, i1_)                                                 \
    {                                                                       \
        const bf16x8 Ta = __builtin_bit_cast(bf16x8, sbuf[bi][(i0_)*64 + l]); \
        const bf16x8 Tb = __builtin_bit_cast(bf16x8, sbuf[bi][(i1_)*64 + l]); \
        const f32x16 u0 = __builtin_amdgcn_mfma_f32_32x32x16_bf16(A, Ta, zacc, 0, 0, 0); \
        const f32x16 u1 = __builtin_amdgcn_mfma_f32_32x32x16_bf16(A, Tb, zacc, 0, 0, 0); \
        _Pragma("unroll")                                                   \
        for (int r = 0; r < 16; ++r)                                        \
            rm[r] = fminf(fminf(rm[r], u0[r]), u1[r]);                      \
    }                                                                       \
    __builtin_amdgcn_sched_barrier(0);

    if (nb > 0){
        STAGE(0, t0)
        __syncthreads();                      // drain initial stage
        int cur = 0;
        for (int bt = 0; bt < nb; ++bt){
            if (bt + 1 < nb){ STAGE(cur ^ 1, t0 + (bt + 1) * 8) }
            PAIRC(cur, 0, 1)
            PAIRC(cur, 2, 3)
            PAIRC(cur, 4, 5)
            PAIRC(cur, 6, 7)
            __syncthreads();                  // waits next batch's loads too
            cur ^= 1;
        }
    }
#undef STAGE
#undef PAIRC

    // leftover tiles (<8) straight from global
    for (int t = t0 + nb * 8; t < t1; ++t){
        const bf16x8 T0 = __builtin_bit_cast(bf16x8, bfp[(size_t)t * 64]);
        const f32x16 u0 = __builtin_amdgcn_mfma_f32_32x32x16_bf16(A, T0, zacc, 0, 0, 0);
#pragma unroll
        for (int r = 0; r < 16; ++r) rm[r] = fminf(rm[r], u0[r]);
    }

    // row-min butterfly within each 32-lane half (cols live across lanes)
#pragma unroll
    for (int r = 0; r < 16; ++r){
        float v = rm[r];
        v = fminf(v, __shfl_xor(v, 1, 64));
        v = fminf(v, __shfl_xor(v, 2, 64));
        v = fminf(v, __shfl_xor(v, 4, 64));
        v = fminf(v, __shfl_xor(v, 8, 64));
        v = fminf(v, __shfl_xor(v, 16, 64));
        rm[r] = v;
    }
    float* __restrict__ rp = rowpart + (size_t)(c * 4 + blockIdx.y) * RSTRIDE;
#pragma unroll
    for (int r = 0; r < 16; ++r){             // static index only (no scratch)
        if ((l & 31) == r){
            const int rowl = (r & 3) + 8 * (r >> 2) + 4 * h;
            const int gr = blockIdx.x * 128 + w * 32 + rowl;
            if (gr < Np) rp[gr] = rm[r];
        }
    }
}

// edge loss + normal consistency + laplacian cot scatter, one dispatch.
__global__ void mesh_k(const float* __restrict__ pred,
                       const int* __restrict__ edges, int E,
                       const int* __restrict__ pairs, int P,
                       const int* __restrict__ faces, int F,
                       int N, int B, float scaleE, float scaleP,
                       float* __restrict__ Lx, float* __restrict__ rowsum,
                       float* __restrict__ accum)
{
    const int tE = B * E, tP = B * P, tF = B * F;
    const int total = tE + tP + tF;
    float se = 0.f, sp = 0.f;
    for (int idx = blockIdx.x * blockDim.x + threadIdx.x; idx < total;
         idx += gridDim.x * blockDim.x) {
        if (idx < tE) {
            const int b = idx / E;
            const int e = idx - b * E;
            const float* __restrict__ vb = pred + (size_t)b * N * 3;
            const int i0 = edges[e * 2 + 0], i1 = edges[e * 2 + 1];
            float dx = vb[i0 * 3 + 0] - vb[i1 * 3 + 0];
            float dy = vb[i0 * 3 + 1] - vb[i1 * 3 + 1];
            float dz = vb[i0 * 3 + 2] - vb[i1 * 3 + 2];
            se += fmaf(dx, dx, fmaf(dy, dy, dz * dz));
        } else if (idx < tE + tP) {
            const int q = idx - tE;
            const int b = q / P;
            const int p = q - b * P;
            const float* __restrict__ vb = pred + (size_t)b * N * 3;
            const int a0 = pairs[p * 4 + 0], a1 = pairs[p * 4 + 1];
            const int a2 = pairs[p * 4 + 2], a3 = pairs[p * 4 + 3];
            float p0x = vb[a0 * 3], p0y = vb[a0 * 3 + 1], p0z = vb[a0 * 3 + 2];
            float ex = vb[a1 * 3] - p0x, ey = vb[a1 * 3 + 1] - p0y, ez = vb[a1 * 3 + 2] - p0z;
            float ux = vb[a2 * 3] - p0x, uy = vb[a2 * 3 + 1] - p0y, uz = vb[a2 * 3 + 2] - p0z;
            float wx = vb[a3 * 3] - p0x, wy = vb[a3 * 3 + 1] - p0y, wz = vb[a3 * 3 + 2] - p0z;
            float n0x = ey * uz - ez * uy;
            float n0y = ez * ux - ex * uz;
            float n0z = ex * uy - ey * ux;
            float n1x = -(ey * wz - ez * wy);
            float n1y = -(ez * wx - ex * wz);
            float n1z = -(ex * wy - ey * wx);
            float dt = n0x * n1x + n0y * n1y + n0z * n1z;
            float l0 = sqrtf(n0x * n0x + n0y * n0y + n0z * n0z);
            float l1 = sqrtf(n1x * n1x + n1y * n1y + n1z * n1z);
            sp += 1.0f - dt / (fmaxf(l0, 1e-8f) * fmaxf(l1, 1e-8f));
        } else {
            const int q = idx - tE - tP;
            const int b = q / F;
            const int f = q - b * F;
            const float* __restrict__ vb = pred + (size_t)b * N * 3;
            const int i0 = faces[f * 3 + 0], i1 = faces[f * 3 + 1], i2 = faces[f * 3 + 2];
            float v0x = vb[i0 * 3], v0y = vb[i0 * 3 + 1], v0z = vb[i0 * 3 + 2];
            float v1x = vb[i1 * 3], v1y = vb[i1 * 3 + 1], v1z = vb[i1 * 3 + 2];
            float v2x = vb[i2 * 3], v2y = vb[i2 * 3 + 1], v2z = vb[i2 * 3 + 2];
            float ax = v1x - v2x, ay = v1y - v2y, az = v1z - v2z;
            float bx = v0x - v2x, by = v0y - v2y, bz = v0z - v2z;
            float cx = v0x - v1x, cy = v0y - v1y, cz = v0z - v1z;
            float A  = sqrtf(ax * ax + ay * ay + az * az);
            float Bl = sqrtf(bx * bx + by * by + bz * bz);
            float C  = sqrtf(cx * cx + cy * cy + cz * cz);
            float s2 = 0.5f * (A + Bl + C);
            float area = sqrtf(fmaxf(s2 * (s2 - A) * (s2 - Bl) * (s2 - C), 1e-12f));
            float A2 = A * A, B2 = Bl * Bl, C2 = C * C;
            float inv4a = 1.0f / (4.0f * area);
            float cota = (B2 + C2 - A2) * inv4a;
            float cotb = (A2 + C2 - B2) * inv4a;
            float cotc = (A2 + B2 - C2) * inv4a;

            float* __restrict__ Lb = Lx + (size_t)b * N * 3;
            float* __restrict__ rb = rowsum + (size_t)b * N;
            #define SCAT(i, j, wv)                                            \
                atomicAdd(&Lb[(i) * 3 + 0], (wv) * vb[(j) * 3 + 0]);          \
                atomicAdd(&Lb[(i) * 3 + 1], (wv) * vb[(j) * 3 + 1]);          \
                atomicAdd(&Lb[(i) * 3 + 2], (wv) * vb[(j) * 3 + 2]);          \
                atomicAdd(&rb[(i)], (wv));
            SCAT(i1, i2, cota) SCAT(i2, i1, cota)
            SCAT(i2, i0, cotb) SCAT(i0, i2, cotb)
            SCAT(i0, i1, cotc) SCAT(i1, i0, cotc)
            #undef SCAT
        }
    }
    se = wave_sum(se);
    sp = wave_sum(sp);
    if ((threadIdx.x & 63) == 0) atomicAdd(accum, fmaf(se, scaleE, sp * scaleP));
}

// rowpart 4-chunk min + clamp + lap residual; last block writes d_out.
__global__ void finalize_k(const float* __restrict__ rowpart,
                           const float* __restrict__ pred, const float* __restrict__ Lx,
                           const float* __restrict__ rowsum,
                           int N, float sMain, float sVel, float scaleL,
                           float* __restrict__ accum, float* __restrict__ out)
{
    const int total = 8 * N + 2 * N;
    float sm = 0.f, sv = 0.f, sl = 0.f;
    for (int idx = blockIdx.x * blockDim.x + threadIdx.x; idx < total;
         idx += gridDim.x * blockDim.x) {
        if (idx < 8 * N) {
            const int c = idx / N, i = idx - c * N;
            const int ds = (c >> 1) & 1;
            if (i < N - ds) {
                const float* rp = rowpart + (size_t)c * 4 * RSTRIDE;
                float v = fminf(fminf(rp[i], rp[RSTRIDE + i]),
                                fminf(rp[2*RSTRIDE + i], rp[3*RSTRIDE + i]));
                float d = fmaxf(v, 0.f);
                if (ds) sv += d; else sm += d;
            }
        } else {
            const int q = idx - 8 * N;       // B*N lap entries
            float rs = rowsum[q];
            float nw = rs > 0.f ? 1.0f / rs : 0.f;
            float rx = Lx[q*3+0]*nw - pred[q*3+0];
            float ry = Lx[q*3+1]*nw - pred[q*3+1];
            float rz = Lx[q*3+2]*nw - pred[q*3+2];
            sl += sqrtf(rx*rx + ry*ry + rz*rz);
        }
    }
    sm = wave_sum(sm); sv = wave_sum(sv); sl = wave_sum(sl);
    if ((threadIdx.x & 63) == 0)
        atomicAdd(accum, fmaf(sm, sMain, fmaf(sv, sVel, sl * scaleL)));

    // last block writes the output (accum[4] is the completion counter,
    // zeroed by bprep_k's ws-zero each launch)
    __syncthreads();
    if (threadIdx.x == 0){
        __threadfence();
        const uint32 prev = atomicAdd((uint32*)(accum + 4), 1u);
        if (prev == gridDim.x - 1)
            out[0] = atomicAdd(accum, 0.0f);   // coherent read of final sum
    }
}

extern "C" void kernel_launch(void* const* d_in, const int* in_sizes, int n_in,
                              void* d_out, int out_size, void* d_ws, size_t ws_size,
                              hipStream_t stream)
{
    const float* pred = (const float*)d_in[0];
    const float* tgt  = (const float*)d_in[1];
    const int* faces  = (const int*)d_in[2];
    const int* edges  = (const int*)d_in[3];
    const int* pairs  = (const int*)d_in[4];

    const int B = 2;
    const int N = in_sizes[0] / (3 * B);   // 8281
    const int F = in_sizes[2] / 3;
    const int E = in_sizes[3] / 2;
    const int P = in_sizes[4] / 4;
    const int NT = (N + 31) >> 5;          // 259

    // workspace layout (4B units):
    // [accum 8 (incl counter at +4)][Lx B*N*3][rowsum B*N][rowpart 32*RSTRIDE][bfrag]
    float* ws      = (float*)d_ws;
    float* accum   = ws;
    float* Lx      = ws + 8;
    float* rowsum  = Lx + (size_t)B * N * 3;
    float* rowpart = rowsum + (size_t)B * N;
    size_t off     = 8 + (size_t)B*N*3 + (size_t)B*N + (size_t)32*RSTRIDE;
    uint4* bfrag   = (uint4*)(ws + off);   // off*4 16B-aligned (off div by 4)

    const int nzero = 8 + B * N * 3 + B * N;

    bprep_k<<<dim3((8 * NT + 3) / 4), dim3(256), 0, stream>>>(pred, tgt, N, bfrag,
                                                              ws, nzero);

    chamfer_mfma_k<<<dim3((N + 127) / 128, 4, 8), dim3(256), 0, stream>>>(
        pred, tgt, N, bfrag, rowpart);

    mesh_k<<<128, dim3(256), 0, stream>>>(pred, edges, E, pairs, P, faces, F, N, B,
                                          W_EDGE / ((float)B * (float)E),
                                          W_NORMAL / ((float)B * (float)P),
                                          Lx, rowsum, accum);

    finalize_k<<<96, dim3(256), 0, stream>>>(rowpart, pred, Lx, rowsum, N,
                                             1.0f / ((float)B * (float)N),
                                             W_VEL / ((float)B * (float)(N - 1)),
                                             W_LAP / ((float)B * (float)N),
                                             accum, (float*)d_out);
}